// Round 1
// baseline (246.041 us; speedup 1.0000x reference)
//
#include <hip/hip_runtime.h>
#include <hip/hip_bf16.h>

// ---------- types ----------
typedef float f32x4 __attribute__((ext_vector_type(4)));
typedef __bf16 bf16x8 __attribute__((ext_vector_type(8)));

// fp32 -> bf16 RNE
__device__ __forceinline__ unsigned short f2bf(float f){
  unsigned int u = __builtin_bit_cast(unsigned int, f);
  u += 0x7fffu + ((u >> 16) & 1u);
  return (unsigned short)(u >> 16);
}

__device__ __forceinline__ void glds16(const void* g, void* l){
  __builtin_amdgcn_global_load_lds((const __attribute__((address_space(1))) void*)g,
                                   (__attribute__((address_space(3))) void*)l, 16, 0, 0);
}

__device__ __forceinline__ f32x4 mfma16(bf16x8 a, bf16x8 b, f32x4 c){
  return __builtin_amdgcn_mfma_f32_16x16x32_bf16(a, b, c, 0, 0, 0);
}

// ---------- kernel: detect mask dtype (bool-bytes vs int32) ----------
// int32 0/1 array: every 32-bit word <= 1.  Random bool bytes: impossible.
__global__ void detect_kernel(const unsigned int* __restrict__ m, int* __restrict__ flag){
  int t = threadIdx.x;
  int bad = 0;
  for(int i = t; i < 4096; i += 256) bad |= (m[i] > 1u);
  unsigned long long b = __ballot(bad != 0);
  __shared__ int sbuf[4];
  if((t & 63) == 0) sbuf[t >> 6] = (b != 0ull);
  __syncthreads();
  if(t == 0) flag[0] = (sbuf[0] | sbuf[1] | sbuf[2] | sbuf[3]) ? 0 : 1; // 1 => int32
}

// ---------- kernel: fp32 -> bf16 convert (4194304 elems, 8/thread) ----------
__global__ void cvt_kernel(const float* __restrict__ src, unsigned short* __restrict__ dst){
  int i = blockIdx.x * 256 + threadIdx.x;   // 0..524287
  const float4* s = (const float4*)src;
  float4 a = s[2*i], b = s[2*i+1];
  union { unsigned short h[8]; uint4 v; } o;
  o.h[0]=f2bf(a.x); o.h[1]=f2bf(a.y); o.h[2]=f2bf(a.z); o.h[3]=f2bf(a.w);
  o.h[4]=f2bf(b.x); o.h[5]=f2bf(b.y); o.h[6]=f2bf(b.z); o.h[7]=f2bf(b.w);
  ((uint4*)dst)[i] = o.v;
}

// ---------- kernel: W[1024][1024] f32 -> W^T bf16 ----------
__global__ void transW_kernel(const float* __restrict__ Wq, const float* __restrict__ Wk,
                              const float* __restrict__ Wv, const float* __restrict__ Wo,
                              unsigned short* __restrict__ WT){
  const float* W = (blockIdx.y==0)?Wq:(blockIdx.y==1)?Wk:(blockIdx.y==2)?Wv:Wo;
  unsigned short* D = WT + (size_t)blockIdx.y * 1048576;
  int r0 = (blockIdx.x >> 4) * 64, c0 = (blockIdx.x & 15) * 64;
  __shared__ unsigned short T[64][65];
  int t = threadIdx.x;
  {
    int r = t >> 2, cb = (t & 3) * 16;
    const float4* src = (const float4*)(W + (size_t)(r0 + r) * 1024 + (c0 + cb));
    float4 v0 = src[0], v1 = src[1], v2 = src[2], v3 = src[3];
    float vals[16] = {v0.x,v0.y,v0.z,v0.w, v1.x,v1.y,v1.z,v1.w,
                      v2.x,v2.y,v2.z,v2.w, v3.x,v3.y,v3.z,v3.w};
    #pragma unroll
    for(int j=0;j<16;j++) T[cb + j][r] = f2bf(vals[j]);
  }
  __syncthreads();
  {
    int c = t >> 2, rb = (t & 3) * 16;
    union { unsigned short h[16]; uint4 v[2]; } o;
    #pragma unroll
    for(int j=0;j<16;j++) o.h[j] = T[c][rb + j];
    uint4* dp = (uint4*)(D + (size_t)(c0 + c) * 1024 + (r0 + rb));
    dp[0] = o.v[0]; dp[1] = o.v[1];
  }
}

// ---------- kernel: C[M=4096][N=1024] = A[4096][1024] @ BT[1024][1024]^T ----------
// bf16 inputs, 128x128 tile, 4 waves (64x64 each), BK=32, glds staging w/ src-swizzle.
template<int OUTF32>
__global__ __launch_bounds__(256,2) void gemm_bt(
    const unsigned short* __restrict__ A0, const unsigned short* __restrict__ A1, const unsigned short* __restrict__ A2,
    const unsigned short* __restrict__ B0, const unsigned short* __restrict__ B1, const unsigned short* __restrict__ B2,
    unsigned short* __restrict__ C0, unsigned short* __restrict__ C1, unsigned short* __restrict__ C2,
    float* __restrict__ Cf)
{
  const unsigned short* A  = (blockIdx.z==0)?A0:(blockIdx.z==1)?A1:A2;
  const unsigned short* BT = (blockIdx.z==0)?B0:(blockIdx.z==1)?B1:B2;
  unsigned short* C        = (blockIdx.z==0)?C0:(blockIdx.z==1)?C1:C2;
  __shared__ unsigned short Asm[128*32];
  __shared__ unsigned short Bsm[128*32];
  const int wid = threadIdx.x >> 6, lane = threadIdx.x & 63;
  const int m0 = blockIdx.x * 128, n0 = blockIdx.y * 128;
  const int wrow = wid >> 1, wcol = wid & 1;
  f32x4 acc[4][4] = {};
  const int sr = lane >> 2;       // staging: row within 16-row chunk
  const int sc = lane & 3;        // staging: 16B-block within 64B row

  for(int kt = 0; kt < 32; ++kt){
    const int kofs = kt * 32;
    #pragma unroll
    for(int i=0;i<2;i++){
      int r = wid*32 + i*16 + sr;            // tile-local row 0..127
      int blk = sc ^ (r & 3);                // source-side swizzle
      glds16(A  + (size_t)(m0 + r)*1024 + kofs + blk*8, &Asm[(wid*32 + i*16)*32]);
      glds16(BT + (size_t)(n0 + r)*1024 + kofs + blk*8, &Bsm[(wid*32 + i*16)*32]);
    }
    __syncthreads();
    bf16x8 af[4], bfv[4];
    #pragma unroll
    for(int fm=0; fm<4; fm++){
      int row = wrow*64 + fm*16 + (lane & 15);
      int blk = (lane >> 4) ^ (row & 3);
      af[fm] = *(const bf16x8*)&Asm[row*32 + blk*8];
    }
    #pragma unroll
    for(int fn=0; fn<4; fn++){
      int row = wcol*64 + fn*16 + (lane & 15);
      int blk = (lane >> 4) ^ (row & 3);
      bfv[fn] = *(const bf16x8*)&Bsm[row*32 + blk*8];
    }
    #pragma unroll
    for(int fm=0; fm<4; fm++)
      #pragma unroll
      for(int fn=0; fn<4; fn++)
        acc[fm][fn] = mfma16(af[fm], bfv[fn], acc[fm][fn]);
    __syncthreads();
  }
  #pragma unroll
  for(int fm=0; fm<4; fm++){
    #pragma unroll
    for(int fn=0; fn<4; fn++){
      int col  = n0 + wcol*64 + fn*16 + (lane & 15);
      int rowb = m0 + wrow*64 + fm*16 + (lane >> 4)*4;
      #pragma unroll
      for(int r=0;r<4;r++){
        if(OUTF32) Cf[(size_t)(rowb + r)*1024 + col] = acc[fm][fn][r];
        else       C [(size_t)(rowb + r)*1024 + col] = f2bf(acc[fm][fn][r]);
      }
    }
  }
}

// ---------- kernel: flash attention ----------
// grid (32 qtiles, 32 bh), 256 thr = 4 waves x 16 q-rows, KVB=64, DK=64.
__global__ __launch_bounds__(256,2) void attn_kernel(
    const unsigned short* __restrict__ Q, const unsigned short* __restrict__ K,
    const unsigned short* __restrict__ V, unsigned short* __restrict__ O,
    const unsigned char* __restrict__ m8, const int* __restrict__ flag)
{
  __shared__ unsigned short Ksm[64*64];
  __shared__ unsigned short Vsm[64*64];
  __shared__ unsigned short Psm[4][16][72];   // per-wave P tile, +8 pad
  const int wid = threadIdx.x >> 6, lane = threadIdx.x & 63;
  const int b = blockIdx.y >> 4, h = blockIdx.y & 15;
  const int q0 = blockIdx.x * 64;
  const int li = lane & 15, lg = lane >> 4;
  const int is32 = flag[0];
  const int* m32 = (const int*)m8;

  bf16x8 qf[2];
  {
    const unsigned short* qp = Q + (size_t)(b*2048 + q0 + wid*16 + li)*1024 + h*64 + lg*8;
    qf[0] = *(const bf16x8*)qp;
    qf[1] = *(const bf16x8*)(qp + 32);
  }
  f32x4 oacc[4] = {};
  float mrow[4], lrow[4];
  #pragma unroll
  for(int j=0;j<4;j++){ mrow[j] = -__builtin_inff(); lrow[j] = 0.f; }
  const size_t mrow0 = (size_t)(b*2048 + q0 + wid*16 + lg*4) * 2048;

  for(int kv0 = 0; kv0 < 2048; kv0 += 64){
    #pragma unroll
    for(int i=0;i<2;i++){
      int r = wid*16 + i*8 + (lane >> 3);
      int blkK = (lane & 7) ^ (lane >> 3);   // swizzled K staging
      glds16(K + (size_t)(b*2048 + kv0 + r)*1024 + h*64 + blkK*8,     &Ksm[(wid*16 + i*8)*64]);
      glds16(V + (size_t)(b*2048 + kv0 + r)*1024 + h*64 + (lane&7)*8, &Vsm[(wid*16 + i*8)*64]);
    }
    __syncthreads();
    // S = Q K^T
    f32x4 sf[4];
    #pragma unroll
    for(int f=0; f<4; f++){
      f32x4 s = {0.f,0.f,0.f,0.f};
      #pragma unroll
      for(int kf=0; kf<2; kf++){
        int row = f*16 + li;
        int blk = (lg + 4*kf) ^ (row & 7);
        bf16x8 kfr = *(const bf16x8*)&Ksm[row*64 + blk*8];
        s = mfma16(qf[kf], kfr, s);
      }
      sf[f] = s;
    }
    // scale + mask
    float pmax[4] = {-__builtin_inff(),-__builtin_inff(),-__builtin_inff(),-__builtin_inff()};
    #pragma unroll
    for(int f=0; f<4; f++){
      int col = kv0 + f*16 + li;
      #pragma unroll
      for(int j=0;j<4;j++){
        float s = sf[f][j] * 0.125f;
        int mv = is32 ? m32[mrow0 + (size_t)j*2048 + col] : (int)m8[mrow0 + (size_t)j*2048 + col];
        s = mv ? -1.0e9f : s;
        sf[f][j] = s;
        pmax[j] = fmaxf(pmax[j], s);
      }
    }
    #pragma unroll
    for(int j=0;j<4;j++){
      #pragma unroll
      for(int d=8; d>=1; d>>=1) pmax[j] = fmaxf(pmax[j], __shfl_xor(pmax[j], d));
    }
    float scal[4], rsum[4];
    #pragma unroll
    for(int j=0;j<4;j++){
      float mn = fmaxf(mrow[j], pmax[j]);
      scal[j] = __expf(mrow[j] - mn);
      mrow[j] = mn;
      rsum[j] = 0.f;
    }
    #pragma unroll
    for(int f=0; f<4; f++)
      #pragma unroll
      for(int j=0;j<4;j++){
        float p = __expf(sf[f][j] - mrow[j]);
        sf[f][j] = p;
        rsum[j] += p;
      }
    #pragma unroll
    for(int j=0;j<4;j++){
      #pragma unroll
      for(int d=8; d>=1; d>>=1) rsum[j] += __shfl_xor(rsum[j], d);
      lrow[j] = lrow[j]*scal[j] + rsum[j];
    }
    #pragma unroll
    for(int d=0; d<4; d++)
      #pragma unroll
      for(int j=0;j<4;j++) oacc[d][j] *= scal[j];
    // P -> LDS (per-wave buffer, no cross-wave dep)
    #pragma unroll
    for(int f=0; f<4; f++)
      #pragma unroll
      for(int j=0;j<4;j++)
        Psm[wid][lg*4 + j][li + 16*f] = f2bf(sf[f][j]);
    // O += P V
    #pragma unroll
    for(int ks=0; ks<2; ks++){
      bf16x8 pf = *(const bf16x8*)&Psm[wid][li][ks*32 + lg*8];
      #pragma unroll
      for(int d=0; d<4; d++){
        union { unsigned short h[8]; bf16x8 v; } vf;
        #pragma unroll
        for(int j=0;j<8;j++) vf.h[j] = Vsm[(ks*32 + lg*8 + j)*64 + li + 16*d];
        oacc[d] = mfma16(pf, vf.v, oacc[d]);
      }
    }
    __syncthreads();
  }
  float inv[4];
  #pragma unroll
  for(int j=0;j<4;j++) inv[j] = 1.0f / lrow[j];
  #pragma unroll
  for(int d=0; d<4; d++)
    #pragma unroll
    for(int j=0;j<4;j++){
      size_t row = (size_t)(b*2048 + q0 + wid*16 + lg*4 + j);
      O[row*1024 + h*64 + 16*d + li] = f2bf(oacc[d][j] * inv[j]);
    }
}

// ---------- launch ----------
extern "C" void kernel_launch(void* const* d_in, const int* in_sizes, int n_in,
                              void* d_out, int out_size, void* d_ws, size_t ws_size,
                              hipStream_t stream)
{
  const float* q_in = (const float*)d_in[0];
  const float* k_in = (const float*)d_in[1];
  const float* v_in = (const float*)d_in[2];
  const unsigned char* mask = (const unsigned char*)d_in[3];
  const float* Wq = (const float*)d_in[4];
  const float* Wk = (const float*)d_in[5];
  const float* Wv = (const float*)d_in[6];
  const float* Wo = (const float*)d_in[7];

  char* ws = (char*)d_ws;
  const size_t MB = 1024*1024;
  int* flag          = (int*)ws;                              // 256 B
  unsigned short* XQ = (unsigned short*)(ws + 256);           // 8 MB
  unsigned short* XK = (unsigned short*)(ws + 256 + 8*MB);    // 8 MB
  unsigned short* XV = (unsigned short*)(ws + 256 + 16*MB);   // 8 MB
  unsigned short* WT = (unsigned short*)(ws + 256 + 24*MB);   // 8 MB (4 matrices)
  unsigned short* Qb = (unsigned short*)(ws + 256 + 32*MB);   // 8 MB
  unsigned short* Kb = (unsigned short*)(ws + 256 + 40*MB);   // 8 MB
  unsigned short* Vb = (unsigned short*)(ws + 256 + 48*MB);   // 8 MB
  unsigned short* Ob = XQ;  // XQ dead after projections; reuse for attention output

  detect_kernel<<<1, 256, 0, stream>>>((const unsigned int*)mask, flag);
  cvt_kernel<<<2048, 256, 0, stream>>>(q_in, XQ);
  cvt_kernel<<<2048, 256, 0, stream>>>(k_in, XK);
  cvt_kernel<<<2048, 256, 0, stream>>>(v_in, XV);
  transW_kernel<<<dim3(256,4), 256, 0, stream>>>(Wq, Wk, Wv, Wo, WT);
  gemm_bt<0><<<dim3(32,8,3), 256, 0, stream>>>(XQ, XK, XV,
                                               WT, WT + 1048576, WT + 2097152,
                                               Qb, Kb, Vb, nullptr);
  attn_kernel<<<dim3(32,32), 256, 0, stream>>>(Qb, Kb, Vb, Ob, mask, flag);
  gemm_bt<1><<<dim3(32,8,1), 256, 0, stream>>>(Ob, Ob, Ob,
                                               WT + 3*1048576, WT + 3*1048576, WT + 3*1048576,
                                               nullptr, nullptr, nullptr, (float*)d_out);
}

// Round 2
// 217.066 us; speedup vs baseline: 1.1335x; 1.1335x over previous
//
#include <hip/hip_runtime.h>
#include <hip/hip_bf16.h>

// ---------- types ----------
typedef float f32x4 __attribute__((ext_vector_type(4)));
typedef __bf16 bf16x8 __attribute__((ext_vector_type(8)));

// fp32 -> bf16 RNE
__device__ __forceinline__ unsigned short f2bf(float f){
  unsigned int u = __builtin_bit_cast(unsigned int, f);
  u += 0x7fffu + ((u >> 16) & 1u);
  return (unsigned short)(u >> 16);
}
__device__ __forceinline__ float bf2f(unsigned short h){
  return __builtin_bit_cast(float, (unsigned int)h << 16);
}

__device__ __forceinline__ void glds16(const void* g, void* l){
  __builtin_amdgcn_global_load_lds((const __attribute__((address_space(1))) void*)g,
                                   (__attribute__((address_space(3))) void*)l, 16, 0, 0);
}

__device__ __forceinline__ f32x4 mfma16(bf16x8 a, bf16x8 b, f32x4 c){
  return __builtin_amdgcn_mfma_f32_16x16x32_bf16(a, b, c, 0, 0, 0);
}

// ---------- kernel: detect mask dtype (bool-bytes vs int32) ----------
__global__ void detect_kernel(const unsigned int* __restrict__ m, int* __restrict__ flag){
  int t = threadIdx.x;
  int bad = 0;
  for(int i = t; i < 4096; i += 256) bad |= (m[i] > 1u);
  unsigned long long b = __ballot(bad != 0);
  __shared__ int sbuf[4];
  if((t & 63) == 0) sbuf[t >> 6] = (b != 0ull);
  __syncthreads();
  if(t == 0) flag[0] = (sbuf[0] | sbuf[1] | sbuf[2] | sbuf[3]) ? 0 : 1; // 1 => int32
}

// ---------- kernel: pack mask into bits (mp[row][64 words]) ----------
__global__ void pack_mask_kernel(const unsigned char* __restrict__ m8,
                                 unsigned int* __restrict__ mp,
                                 const int* __restrict__ flag){
  const int wid = threadIdx.x >> 6, lane = threadIdx.x & 63;
  const int row = blockIdx.x * 4 + wid;            // 0..4095 (b*2048+q)
  const int is32 = flag[0];
  const int* m32 = (const int*)m8;
  for(int c0 = 0; c0 < 2048; c0 += 64){
    int mv = is32 ? m32[(size_t)row*2048 + c0 + lane]
                  : (int)m8[(size_t)row*2048 + c0 + lane];
    unsigned long long b = __ballot(mv != 0);
    if(lane == 0){
      mp[(size_t)row*64 + (c0 >> 5)]     = (unsigned int)b;
      mp[(size_t)row*64 + (c0 >> 5) + 1] = (unsigned int)(b >> 32);
    }
  }
}

// ---------- kernel: fp32 -> bf16 convert ----------
__global__ void cvt_kernel(const float* __restrict__ src, unsigned short* __restrict__ dst){
  int i = blockIdx.x * 256 + threadIdx.x;
  const float4* s = (const float4*)src;
  float4 a = s[2*i], b = s[2*i+1];
  union { unsigned short h[8]; uint4 v; } o;
  o.h[0]=f2bf(a.x); o.h[1]=f2bf(a.y); o.h[2]=f2bf(a.z); o.h[3]=f2bf(a.w);
  o.h[4]=f2bf(b.x); o.h[5]=f2bf(b.y); o.h[6]=f2bf(b.z); o.h[7]=f2bf(b.w);
  ((uint4*)dst)[i] = o.v;
}

// ---------- kernel: W[1024][1024] f32 -> W^T bf16 ----------
__global__ void transW_kernel(const float* __restrict__ Wq, const float* __restrict__ Wk,
                              const float* __restrict__ Wv, const float* __restrict__ Wo,
                              unsigned short* __restrict__ WT){
  const float* W = (blockIdx.y==0)?Wq:(blockIdx.y==1)?Wk:(blockIdx.y==2)?Wv:Wo;
  unsigned short* D = WT + (size_t)blockIdx.y * 1048576;
  int r0 = (blockIdx.x >> 4) * 64, c0 = (blockIdx.x & 15) * 64;
  __shared__ unsigned short T[64][65];
  int t = threadIdx.x;
  {
    int r = t >> 2, cb = (t & 3) * 16;
    const float4* src = (const float4*)(W + (size_t)(r0 + r) * 1024 + (c0 + cb));
    float4 v0 = src[0], v1 = src[1], v2 = src[2], v3 = src[3];
    float vals[16] = {v0.x,v0.y,v0.z,v0.w, v1.x,v1.y,v1.z,v1.w,
                      v2.x,v2.y,v2.z,v2.w, v3.x,v3.y,v3.z,v3.w};
    #pragma unroll
    for(int j=0;j<16;j++) T[cb + j][r] = f2bf(vals[j]);
  }
  __syncthreads();
  {
    int c = t >> 2, rb = (t & 3) * 16;
    union { unsigned short h[16]; uint4 v[2]; } o;
    #pragma unroll
    for(int j=0;j<16;j++) o.h[j] = T[c][rb + j];
    uint4* dp = (uint4*)(D + (size_t)(c0 + c) * 1024 + (r0 + rb));
    dp[0] = o.v[0]; dp[1] = o.v[1];
  }
}

// ---------- kernel: per-head transpose Vb[token][1024] -> Vt[bh*64+d][2048] ----------
__global__ void transV_kernel(const unsigned short* __restrict__ Vb,
                              unsigned short* __restrict__ Vt){
  const int bh = blockIdx.y, b = bh >> 4, h = bh & 15;
  const int s0 = blockIdx.x * 64;
  __shared__ unsigned short T[64][68];
  const int t = threadIdx.x;
  {
    int r = t >> 2, cb = (t & 3) * 16;
    const uint4* src = (const uint4*)(Vb + (size_t)(b*2048 + s0 + r)*1024 + h*64 + cb);
    union { unsigned short h[16]; uint4 v[2]; } o;
    o.v[0] = src[0]; o.v[1] = src[1];
    uint2* dst = (uint2*)&T[r][cb];
    const uint2* sv = (const uint2*)o.h;
    dst[0]=sv[0]; dst[1]=sv[1]; dst[2]=sv[2]; dst[3]=sv[3];
  }
  __syncthreads();
  {
    int c = t >> 2, sb = (t & 3) * 16;
    union { unsigned short h[16]; uint4 v[2]; } o;
    #pragma unroll
    for(int j=0;j<16;j++) o.h[j] = T[sb + j][c];
    uint4* dp = (uint4*)(Vt + (size_t)(bh*64 + c)*2048 + s0 + sb);
    dp[0] = o.v[0]; dp[1] = o.v[1];
  }
}

// ---------- kernel: C[M=4096][N=1024] = A @ BT^T, bf16, 128x128 tile ----------
template<int OUTF32>
__global__ __launch_bounds__(256,2) void gemm_bt(
    const unsigned short* __restrict__ A0, const unsigned short* __restrict__ A1, const unsigned short* __restrict__ A2,
    const unsigned short* __restrict__ B0, const unsigned short* __restrict__ B1, const unsigned short* __restrict__ B2,
    unsigned short* __restrict__ C0, unsigned short* __restrict__ C1, unsigned short* __restrict__ C2,
    float* __restrict__ Cf)
{
  const unsigned short* A  = (blockIdx.z==0)?A0:(blockIdx.z==1)?A1:A2;
  const unsigned short* BT = (blockIdx.z==0)?B0:(blockIdx.z==1)?B1:B2;
  unsigned short* C        = (blockIdx.z==0)?C0:(blockIdx.z==1)?C1:C2;
  __shared__ unsigned short Asm[128*32];
  __shared__ unsigned short Bsm[128*32];
  const int wid = threadIdx.x >> 6, lane = threadIdx.x & 63;
  const int m0 = blockIdx.x * 128, n0 = blockIdx.y * 128;
  const int wrow = wid >> 1, wcol = wid & 1;
  f32x4 acc[4][4] = {};
  const int sr = lane >> 2;
  const int sc = lane & 3;

  for(int kt = 0; kt < 32; ++kt){
    const int kofs = kt * 32;
    #pragma unroll
    for(int i=0;i<2;i++){
      int r = wid*32 + i*16 + sr;
      int blk = sc ^ (r & 3);
      glds16(A  + (size_t)(m0 + r)*1024 + kofs + blk*8, &Asm[(wid*32 + i*16)*32]);
      glds16(BT + (size_t)(n0 + r)*1024 + kofs + blk*8, &Bsm[(wid*32 + i*16)*32]);
    }
    __syncthreads();
    bf16x8 af[4], bfv[4];
    #pragma unroll
    for(int fm=0; fm<4; fm++){
      int row = wrow*64 + fm*16 + (lane & 15);
      int blk = (lane >> 4) ^ (row & 3);
      af[fm] = *(const bf16x8*)&Asm[row*32 + blk*8];
    }
    #pragma unroll
    for(int fn=0; fn<4; fn++){
      int row = wcol*64 + fn*16 + (lane & 15);
      int blk = (lane >> 4) ^ (row & 3);
      bfv[fn] = *(const bf16x8*)&Bsm[row*32 + blk*8];
    }
    __builtin_amdgcn_s_setprio(1);
    #pragma unroll
    for(int fm=0; fm<4; fm++)
      #pragma unroll
      for(int fn=0; fn<4; fn++)
        acc[fm][fn] = mfma16(af[fm], bfv[fn], acc[fm][fn]);
    __builtin_amdgcn_s_setprio(0);
    __syncthreads();
  }
  #pragma unroll
  for(int fm=0; fm<4; fm++){
    #pragma unroll
    for(int fn=0; fn<4; fn++){
      int col  = n0 + wcol*64 + fn*16 + (lane & 15);
      int rowb = m0 + wrow*64 + fm*16 + (lane >> 4)*4;
      #pragma unroll
      for(int r=0;r<4;r++){
        if(OUTF32) Cf[(size_t)(rowb + r)*1024 + col] = acc[fm][fn][r];
        else       C [(size_t)(rowb + r)*1024 + col] = f2bf(acc[fm][fn][r]);
      }
    }
  }
}

// ---------- kernel: flash attention v2 ----------
// grid 1024 (swizzled -> 32 qtiles x 32 bh), 4 waves x 16 q-rows, KVB=64, DK=64.
// K and Vt staged double-buffered via global_load_lds (src-swizzled), packed-bit mask.
__global__ __launch_bounds__(256,3) void attn_kernel(
    const unsigned short* __restrict__ Q, const unsigned short* __restrict__ K,
    const unsigned short* __restrict__ Vt, unsigned short* __restrict__ O,
    const unsigned int* __restrict__ mp)
{
  __shared__ unsigned short Ksm[2][64*64];
  __shared__ unsigned short Vsm[2][64*64];
  __shared__ unsigned short Psm[4][16][72];
  const int wid = threadIdx.x >> 6, lane = threadIdx.x & 63;
  // XCD-aware swizzle: colocate all q-tiles of a head on one XCD
  const int orig = blockIdx.x;
  const int wg = (orig & 7) * 128 + (orig >> 3);
  const int qt = wg & 31, bh = wg >> 5;
  const int b = bh >> 4, h = bh & 15;
  const int q0 = qt * 64;
  const int li = lane & 15, lg = lane >> 4;

  // Q fragments, pre-scaled by 1/sqrt(64)=0.125 (exact in bf16)
  bf16x8 qf[2];
  {
    const unsigned short* qp = Q + (size_t)(b*2048 + q0 + wid*16 + li)*1024 + h*64 + lg*8;
    union { unsigned short s[8]; bf16x8 v; } u0, u1;
    u0.v = *(const bf16x8*)qp; u1.v = *(const bf16x8*)(qp + 32);
    #pragma unroll
    for(int j=0;j<8;j++){
      u0.s[j] = f2bf(bf2f(u0.s[j]) * 0.125f);
      u1.s[j] = f2bf(bf2f(u1.s[j]) * 0.125f);
    }
    qf[0] = u0.v; qf[1] = u1.v;
  }

  f32x4 oacc[4] = {};
  float mrow[4], lrow[4];
  #pragma unroll
  for(int j=0;j<4;j++){ mrow[j] = -__builtin_inff(); lrow[j] = 0.f; }

  const int srow = lane >> 3;                 // 0..7
  const int sblk = (lane & 7) ^ srow;         // source-side swizzle block
  const size_t mbase = (size_t)(b*2048 + q0 + wid*16 + lg*4) * 64;

  // stage tile 0
  #pragma unroll
  for(int i=0;i<2;i++){
    int r = wid*16 + i*8 + srow;
    glds16(K  + (size_t)(b*2048 + r)*1024 + h*64 + sblk*8, &Ksm[0][(wid*16 + i*8)*64]);
    glds16(Vt + (size_t)(bh*64 + r)*2048 + sblk*8,         &Vsm[0][(wid*16 + i*8)*64]);
  }
  uint2 mw[4], mwn[4];
  #pragma unroll
  for(int j=0;j<4;j++) mw[j] = *(const uint2*)&mp[mbase + (size_t)j*64];
  __syncthreads();

  int buf = 0;
  for(int t = 0; t < 32; ++t){
    const int kv0 = t * 64;
    if(t < 31){
      #pragma unroll
      for(int i=0;i<2;i++){
        int r = wid*16 + i*8 + srow;
        glds16(K  + (size_t)(b*2048 + kv0 + 64 + r)*1024 + h*64 + sblk*8, &Ksm[buf^1][(wid*16 + i*8)*64]);
        glds16(Vt + (size_t)(bh*64 + r)*2048 + kv0 + 64 + sblk*8,         &Vsm[buf^1][(wid*16 + i*8)*64]);
      }
      #pragma unroll
      for(int j=0;j<4;j++) mwn[j] = *(const uint2*)&mp[mbase + (size_t)j*64 + ((kv0 + 64) >> 5)];
    }
    // S = (Q/8) K^T
    f32x4 sf[4];
    __builtin_amdgcn_s_setprio(1);
    #pragma unroll
    for(int f=0; f<4; f++){
      f32x4 s = {0.f,0.f,0.f,0.f};
      #pragma unroll
      for(int kf=0; kf<2; kf++){
        int blk = (lg + 4*kf) ^ (li & 7);
        bf16x8 kfr = *(const bf16x8*)&Ksm[buf][(f*16 + li)*64 + blk*8];
        s = mfma16(qf[kf], kfr, s);
      }
      sf[f] = s;
    }
    __builtin_amdgcn_s_setprio(0);
    // mask via packed bits + row max
    float pmax[4] = {-__builtin_inff(),-__builtin_inff(),-__builtin_inff(),-__builtin_inff()};
    #pragma unroll
    for(int f=0; f<4; f++){
      #pragma unroll
      for(int j=0;j<4;j++){
        unsigned int w = (f < 2) ? mw[j].x : mw[j].y;
        unsigned int bit = (w >> ((f & 1)*16 + li)) & 1u;
        float s = bit ? -1.0e9f : sf[f][j];
        sf[f][j] = s;
        pmax[j] = fmaxf(pmax[j], s);
      }
    }
    #pragma unroll
    for(int j=0;j<4;j++){
      #pragma unroll
      for(int d=8; d>=1; d>>=1) pmax[j] = fmaxf(pmax[j], __shfl_xor(pmax[j], d));
    }
    float scal[4];
    #pragma unroll
    for(int j=0;j<4;j++){
      float mn = fmaxf(mrow[j], pmax[j]);
      scal[j] = __expf(mrow[j] - mn);
      mrow[j] = mn;
    }
    #pragma unroll
    for(int j=0;j<4;j++){
      float rs = 0.f;
      #pragma unroll
      for(int f=0; f<4; f++){
        float p = __expf(sf[f][j] - mrow[j]);
        sf[f][j] = p;
        rs += p;
      }
      lrow[j] = lrow[j]*scal[j] + rs;   // lane-partial sum; reduced at end
    }
    #pragma unroll
    for(int d=0; d<4; d++)
      #pragma unroll
      for(int j=0;j<4;j++) oacc[d][j] *= scal[j];
    // P -> LDS (per-wave buffer)
    #pragma unroll
    for(int f=0; f<4; f++)
      #pragma unroll
      for(int j=0;j<4;j++)
        Psm[wid][lg*4 + j][f*16 + li] = f2bf(sf[f][j]);
    // O += P V  (V fragments now vector b128 reads from transposed V)
    __builtin_amdgcn_s_setprio(1);
    #pragma unroll
    for(int ks=0; ks<2; ks++){
      bf16x8 pf = *(const bf16x8*)&Psm[wid][li][ks*32 + lg*8];
      #pragma unroll
      for(int d=0; d<4; d++){
        int blk = ((ks*4 + lg) ^ (li & 7));
        bf16x8 vf = *(const bf16x8*)&Vsm[buf][(d*16 + li)*64 + blk*8];
        oacc[d] = mfma16(pf, vf, oacc[d]);
      }
    }
    __builtin_amdgcn_s_setprio(0);
    __syncthreads();
    #pragma unroll
    for(int j=0;j<4;j++) mw[j] = mwn[j];
    buf ^= 1;
  }
  // final: reduce row sums across the 16 lanes, normalize, store
  float inv[4];
  #pragma unroll
  for(int j=0;j<4;j++){
    float rs = lrow[j];
    #pragma unroll
    for(int d=8; d>=1; d>>=1) rs += __shfl_xor(rs, d);
    inv[j] = 1.0f / rs;
  }
  #pragma unroll
  for(int d=0; d<4; d++)
    #pragma unroll
    for(int j=0;j<4;j++){
      size_t row = (size_t)(b*2048 + q0 + wid*16 + lg*4 + j);
      O[row*1024 + h*64 + 16*d + li] = f2bf(oacc[d][j] * inv[j]);
    }
}

// ---------- launch ----------
extern "C" void kernel_launch(void* const* d_in, const int* in_sizes, int n_in,
                              void* d_out, int out_size, void* d_ws, size_t ws_size,
                              hipStream_t stream)
{
  const float* q_in = (const float*)d_in[0];
  const float* k_in = (const float*)d_in[1];
  const float* v_in = (const float*)d_in[2];
  const unsigned char* mask = (const unsigned char*)d_in[3];
  const float* Wq = (const float*)d_in[4];
  const float* Wk = (const float*)d_in[5];
  const float* Wv = (const float*)d_in[6];
  const float* Wo = (const float*)d_in[7];

  char* ws = (char*)d_ws;
  const size_t MB = 1024*1024;
  int* flag          = (int*)ws;                              // 256 B
  unsigned short* XQ = (unsigned short*)(ws + 256);           // 8 MB
  unsigned short* XK = (unsigned short*)(ws + 256 + 8*MB);    // 8 MB
  unsigned short* XV = (unsigned short*)(ws + 256 + 16*MB);   // 8 MB
  unsigned short* WT = (unsigned short*)(ws + 256 + 24*MB);   // 8 MB (4 matrices)
  unsigned short* Qb = (unsigned short*)(ws + 256 + 32*MB);   // 8 MB
  unsigned short* Kb = (unsigned short*)(ws + 256 + 40*MB);   // 8 MB
  unsigned short* Vb = (unsigned short*)(ws + 256 + 48*MB);   // 8 MB
  // regions dead after the projection GEMM get reused:
  unsigned short* Ob = XQ;                                    // attention output
  unsigned short* Vt = XK;                                    // transposed V (8 MB)
  unsigned int*   mpk= (unsigned int*)XV;                     // packed mask (2 MB)

  detect_kernel<<<1, 256, 0, stream>>>((const unsigned int*)mask, flag);
  cvt_kernel<<<2048, 256, 0, stream>>>(q_in, XQ);
  cvt_kernel<<<2048, 256, 0, stream>>>(k_in, XK);
  cvt_kernel<<<2048, 256, 0, stream>>>(v_in, XV);
  transW_kernel<<<dim3(256,4), 256, 0, stream>>>(Wq, Wk, Wv, Wo, WT);
  gemm_bt<0><<<dim3(32,8,3), 256, 0, stream>>>(XQ, XK, XV,
                                               WT, WT + 1048576, WT + 2097152,
                                               Qb, Kb, Vb, nullptr);
  transV_kernel<<<dim3(32,32), 256, 0, stream>>>(Vb, Vt);
  pack_mask_kernel<<<1024, 256, 0, stream>>>(mask, mpk, flag);
  attn_kernel<<<1024, 256, 0, stream>>>(Qb, Kb, Vt, Ob, mpk);
  gemm_bt<1><<<dim3(32,8,1), 256, 0, stream>>>(Ob, Ob, Ob,
                                               WT + 3*1048576, WT + 3*1048576, WT + 3*1048576,
                                               nullptr, nullptr, nullptr, (float*)d_out);
}

// Round 3
// 171.499 us; speedup vs baseline: 1.4347x; 1.2657x over previous
//
#include <hip/hip_runtime.h>
#include <hip/hip_bf16.h>

// ---------- types ----------
typedef float f32x4 __attribute__((ext_vector_type(4)));
typedef __bf16 bf16x8 __attribute__((ext_vector_type(8)));

// fp32 -> bf16 RNE
__device__ __forceinline__ unsigned short f2bf(float f){
  unsigned int u = __builtin_bit_cast(unsigned int, f);
  u += 0x7fffu + ((u >> 16) & 1u);
  return (unsigned short)(u >> 16);
}
__device__ __forceinline__ float bf2f(unsigned short h){
  return __builtin_bit_cast(float, (unsigned int)h << 16);
}

__device__ __forceinline__ void glds16(const void* g, void* l){
  __builtin_amdgcn_global_load_lds((const __attribute__((address_space(1))) void*)g,
                                   (__attribute__((address_space(3))) void*)l, 16, 0, 0);
}

__device__ __forceinline__ f32x4 mfma16(bf16x8 a, bf16x8 b, f32x4 c){
  return __builtin_amdgcn_mfma_f32_16x16x32_bf16(a, b, c, 0, 0, 0);
}

// exp2 (v_exp_f32 is natively 2^x)
#if __has_builtin(__builtin_amdgcn_exp2f)
__device__ __forceinline__ float exp2v(float x){ return __builtin_amdgcn_exp2f(x); }
#else
__device__ __forceinline__ float exp2v(float x){ return exp2f(x); }
#endif

// packed f32x2 -> bf16x2 (gfx950)
__device__ __forceinline__ unsigned int cvtpk(float a, float b){
  unsigned int r;
  asm("v_cvt_pk_bf16_f32 %0, %1, %2" : "=v"(r) : "v"(a), "v"(b));
  return r;
}

// ---------- kernel: detect mask dtype (bool-bytes vs int32) ----------
__global__ void detect_kernel(const unsigned int* __restrict__ m, int* __restrict__ flag){
  int t = threadIdx.x;
  int bad = 0;
  for(int i = t; i < 4096; i += 256) bad |= (m[i] > 1u);
  unsigned long long b = __ballot(bad != 0);
  __shared__ int sbuf[4];
  if((t & 63) == 0) sbuf[t >> 6] = (b != 0ull);
  __syncthreads();
  if(t == 0) flag[0] = (sbuf[0] | sbuf[1] | sbuf[2] | sbuf[3]) ? 0 : 1; // 1 => int32
}

// ---------- kernel: pack mask into bits (mp[row][64 words]) ----------
__global__ void pack_mask_kernel(const unsigned char* __restrict__ m8,
                                 unsigned int* __restrict__ mp,
                                 const int* __restrict__ flag){
  const int wid = threadIdx.x >> 6, lane = threadIdx.x & 63;
  const int row = blockIdx.x * 4 + wid;            // 0..4095 (b*2048+q)
  const int is32 = flag[0];
  const int* m32 = (const int*)m8;
  for(int c0 = 0; c0 < 2048; c0 += 64){
    int mv = is32 ? m32[(size_t)row*2048 + c0 + lane]
                  : (int)m8[(size_t)row*2048 + c0 + lane];
    unsigned long long b = __ballot(mv != 0);
    if(lane == 0){
      mp[(size_t)row*64 + (c0 >> 5)]     = (unsigned int)b;
      mp[(size_t)row*64 + (c0 >> 5) + 1] = (unsigned int)(b >> 32);
    }
  }
}

// ---------- kernel: fp32 -> bf16 convert ----------
__global__ void cvt_kernel(const float* __restrict__ src, unsigned short* __restrict__ dst){
  int i = blockIdx.x * 256 + threadIdx.x;
  const float4* s = (const float4*)src;
  float4 a = s[2*i], b = s[2*i+1];
  union { unsigned short h[8]; uint4 v; } o;
  o.h[0]=f2bf(a.x); o.h[1]=f2bf(a.y); o.h[2]=f2bf(a.z); o.h[3]=f2bf(a.w);
  o.h[4]=f2bf(b.x); o.h[5]=f2bf(b.y); o.h[6]=f2bf(b.z); o.h[7]=f2bf(b.w);
  ((uint4*)dst)[i] = o.v;
}

// ---------- kernel: W[1024][1024] f32 -> W^T bf16 ----------
__global__ void transW_kernel(const float* __restrict__ Wq, const float* __restrict__ Wk,
                              const float* __restrict__ Wv, const float* __restrict__ Wo,
                              unsigned short* __restrict__ WT){
  const float* W = (blockIdx.y==0)?Wq:(blockIdx.y==1)?Wk:(blockIdx.y==2)?Wv:Wo;
  unsigned short* D = WT + (size_t)blockIdx.y * 1048576;
  int r0 = (blockIdx.x >> 4) * 64, c0 = (blockIdx.x & 15) * 64;
  __shared__ unsigned short T[64][65];
  int t = threadIdx.x;
  {
    int r = t >> 2, cb = (t & 3) * 16;
    const float4* src = (const float4*)(W + (size_t)(r0 + r) * 1024 + (c0 + cb));
    float4 v0 = src[0], v1 = src[1], v2 = src[2], v3 = src[3];
    float vals[16] = {v0.x,v0.y,v0.z,v0.w, v1.x,v1.y,v1.z,v1.w,
                      v2.x,v2.y,v2.z,v2.w, v3.x,v3.y,v3.z,v3.w};
    #pragma unroll
    for(int j=0;j<16;j++) T[cb + j][r] = f2bf(vals[j]);
  }
  __syncthreads();
  {
    int c = t >> 2, rb = (t & 3) * 16;
    union { unsigned short h[16]; uint4 v[2]; } o;
    #pragma unroll
    for(int j=0;j<16;j++) o.h[j] = T[c][rb + j];
    uint4* dp = (uint4*)(D + (size_t)(c0 + c) * 1024 + (r0 + rb));
    dp[0] = o.v[0]; dp[1] = o.v[1];
  }
}

// ---------- kernel: per-head transpose Vb[token][1024] -> Vt[bh*64+d][2048] ----------
__global__ void transV_kernel(const unsigned short* __restrict__ Vb,
                              unsigned short* __restrict__ Vt){
  const int bh = blockIdx.y, b = bh >> 4, h = bh & 15;
  const int s0 = blockIdx.x * 64;
  __shared__ unsigned short T[64][68];
  const int t = threadIdx.x;
  {
    int r = t >> 2, cb = (t & 3) * 16;
    const uint4* src = (const uint4*)(Vb + (size_t)(b*2048 + s0 + r)*1024 + h*64 + cb);
    union { unsigned short h[16]; uint4 v[2]; } o;
    o.v[0] = src[0]; o.v[1] = src[1];
    uint2* dst = (uint2*)&T[r][cb];
    const uint2* sv = (const uint2*)o.h;
    dst[0]=sv[0]; dst[1]=sv[1]; dst[2]=sv[2]; dst[3]=sv[3];
  }
  __syncthreads();
  {
    int c = t >> 2, sb = (t & 3) * 16;
    union { unsigned short h[16]; uint4 v[2]; } o;
    #pragma unroll
    for(int j=0;j<16;j++) o.h[j] = T[sb + j][c];
    uint4* dp = (uint4*)(Vt + (size_t)(bh*64 + c)*2048 + s0 + sb);
    dp[0] = o.v[0]; dp[1] = o.v[1];
  }
}

// ---------- kernel: C[M=4096][N=1024] = A @ BT^T, bf16, 128x128 tile ----------
template<int OUTF32>
__global__ __launch_bounds__(256,2) void gemm_bt(
    const unsigned short* __restrict__ A0, const unsigned short* __restrict__ A1, const unsigned short* __restrict__ A2,
    const unsigned short* __restrict__ B0, const unsigned short* __restrict__ B1, const unsigned short* __restrict__ B2,
    unsigned short* __restrict__ C0, unsigned short* __restrict__ C1, unsigned short* __restrict__ C2,
    float* __restrict__ Cf)
{
  const unsigned short* A  = (blockIdx.z==0)?A0:(blockIdx.z==1)?A1:A2;
  const unsigned short* BT = (blockIdx.z==0)?B0:(blockIdx.z==1)?B1:B2;
  unsigned short* C        = (blockIdx.z==0)?C0:(blockIdx.z==1)?C1:C2;
  __shared__ unsigned short Asm[128*32];
  __shared__ unsigned short Bsm[128*32];
  const int wid = threadIdx.x >> 6, lane = threadIdx.x & 63;
  const int m0 = blockIdx.x * 128, n0 = blockIdx.y * 128;
  const int wrow = wid >> 1, wcol = wid & 1;
  f32x4 acc[4][4] = {};
  const int sr = lane >> 2;
  const int sc = lane & 3;

  for(int kt = 0; kt < 32; ++kt){
    const int kofs = kt * 32;
    #pragma unroll
    for(int i=0;i<2;i++){
      int r = wid*32 + i*16 + sr;
      int blk = sc ^ (r & 3);
      glds16(A  + (size_t)(m0 + r)*1024 + kofs + blk*8, &Asm[(wid*32 + i*16)*32]);
      glds16(BT + (size_t)(n0 + r)*1024 + kofs + blk*8, &Bsm[(wid*32 + i*16)*32]);
    }
    __syncthreads();
    bf16x8 af[4], bfv[4];
    #pragma unroll
    for(int fm=0; fm<4; fm++){
      int row = wrow*64 + fm*16 + (lane & 15);
      int blk = (lane >> 4) ^ (row & 3);
      af[fm] = *(const bf16x8*)&Asm[row*32 + blk*8];
    }
    #pragma unroll
    for(int fn=0; fn<4; fn++){
      int row = wcol*64 + fn*16 + (lane & 15);
      int blk = (lane >> 4) ^ (row & 3);
      bfv[fn] = *(const bf16x8*)&Bsm[row*32 + blk*8];
    }
    __builtin_amdgcn_s_setprio(1);
    #pragma unroll
    for(int fm=0; fm<4; fm++)
      #pragma unroll
      for(int fn=0; fn<4; fn++)
        acc[fm][fn] = mfma16(af[fm], bfv[fn], acc[fm][fn]);
    __builtin_amdgcn_s_setprio(0);
    __syncthreads();
  }
  #pragma unroll
  for(int fm=0; fm<4; fm++){
    #pragma unroll
    for(int fn=0; fn<4; fn++){
      int col  = n0 + wcol*64 + fn*16 + (lane & 15);
      int rowb = m0 + wrow*64 + fm*16 + (lane >> 4)*4;
      #pragma unroll
      for(int r=0;r<4;r++){
        if(OUTF32) Cf[(size_t)(rowb + r)*1024 + col] = acc[fm][fn][r];
        else       C [(size_t)(rowb + r)*1024 + col] = f2bf(acc[fm][fn][r]);
      }
    }
  }
}

// ---------- kernel: flash attention v3 (swapped QK^T, in-register softmax) ----------
// grid 1024 (swizzled -> 32 qtiles x 32 bh), 4 waves x 16 q-rows, KVB=64, DK=64.
// S^T = mfma(K, Q): lane (li,lg) holds S[q=wid*16+li][k=f*16+lg*4+j] -> row-local softmax.
__global__ __launch_bounds__(256,4) void attn_kernel(
    const unsigned short* __restrict__ Q, const unsigned short* __restrict__ K,
    const unsigned short* __restrict__ Vt, unsigned short* __restrict__ O,
    const unsigned int* __restrict__ mp)
{
  __shared__ unsigned short Ksm[2][64*64];
  __shared__ unsigned short Vsm[2][64*64];
  __shared__ unsigned short Psm[4][16][64];   // per-wave, XOR-swizzled 16B blocks
  const int wid = threadIdx.x >> 6, lane = threadIdx.x & 63;
  const int orig = blockIdx.x;
  const int wg = (orig & 7) * 128 + (orig >> 3);   // XCD swizzle (1024 % 8 == 0)
  const int qt = wg & 31, bh = wg >> 5;
  const int b = bh >> 4, h = bh & 15;
  const int q0 = qt * 64;
  const int li = lane & 15, lg = lane >> 4;

  // Q fragment pre-scaled by 0.125*log2(e)  -> scores in log2 domain
  bf16x8 qf[2];
  {
    const unsigned short* qp = Q + (size_t)(b*2048 + q0 + wid*16 + li)*1024 + h*64 + lg*8;
    union { unsigned short s[8]; bf16x8 v; } u0, u1;
    u0.v = *(const bf16x8*)qp; u1.v = *(const bf16x8*)(qp + 32);
    #pragma unroll
    for(int j=0;j<8;j++){
      u0.s[j] = f2bf(bf2f(u0.s[j]) * 0.1803368801111601f);
      u1.s[j] = f2bf(bf2f(u1.s[j]) * 0.1803368801111601f);
    }
    qf[0] = u0.v; qf[1] = u1.v;
  }

  f32x4 oacc[4] = {};
  float mrow = -__builtin_inff();
  float lrow = 0.f;                      // lane-partial row sum (quad-reduced at end)

  const int srow = lane >> 3;
  const int sblk = (lane & 7) ^ srow;    // source-side swizzle for K/V staging
  const int mrowg = b*2048 + q0 + wid*16 + li;   // this lane's q-row (mask row)
  const int li7 = li & 7;

  // stage tile 0
  #pragma unroll
  for(int i=0;i<2;i++){
    int r = wid*16 + i*8 + srow;
    glds16(K  + (size_t)(b*2048 + r)*1024 + h*64 + sblk*8, &Ksm[0][(wid*16 + i*8)*64]);
    glds16(Vt + (size_t)(bh*64 + r)*2048 + sblk*8,         &Vsm[0][(wid*16 + i*8)*64]);
  }
  uint2 mw = *(const uint2*)&mp[(size_t)mrowg*64];
  uint2 mwn;
  __syncthreads();

  int buf = 0;
  for(int t = 0; t < 32; ++t){
    const int kv0 = t * 64;
    if(t < 31){
      #pragma unroll
      for(int i=0;i<2;i++){
        int r = wid*16 + i*8 + srow;
        glds16(K  + (size_t)(b*2048 + kv0 + 64 + r)*1024 + h*64 + sblk*8, &Ksm[buf^1][(wid*16 + i*8)*64]);
        glds16(Vt + (size_t)(bh*64 + r)*2048 + kv0 + 64 + sblk*8,         &Vsm[buf^1][(wid*16 + i*8)*64]);
      }
      mwn = *(const uint2*)&mp[(size_t)mrowg*64 + (size_t)((kv0 + 64) >> 5)];
    }
    // S^T tiles: p[f][j] = S[q=li][k=f*16+lg*4+j] (log2 domain)
    float p[4][4];
    __builtin_amdgcn_s_setprio(1);
    #pragma unroll
    for(int f=0; f<4; f++){
      f32x4 s = {0.f,0.f,0.f,0.f};
      #pragma unroll
      for(int kf=0; kf<2; kf++){
        int blk = (kf*4 + lg) ^ li7;
        bf16x8 kfr = *(const bf16x8*)&Ksm[buf][(f*16 + li)*64 + blk*8];
        s = mfma16(kfr, qf[kf], s);     // swapped operands
      }
      #pragma unroll
      for(int j=0;j<4;j++) p[f][j] = s[j];
    }
    __builtin_amdgcn_s_setprio(0);
    // mask (packed bits; lane owns one q-row)
    #pragma unroll
    for(int f=0; f<4; f++){
      unsigned int w = (f < 2) ? mw.x : mw.y;
      #pragma unroll
      for(int j=0;j<4;j++){
        unsigned int bit = (w >> ((f & 1)*16 + lg*4 + j)) & 1u;
        p[f][j] = bit ? -1.0e9f : p[f][j];
      }
    }
    // tile max (per-thread tree + 2 shfl across the quad)
    float tmax;
    {
      float m0 = fmaxf(fmaxf(p[0][0],p[0][1]), fmaxf(p[0][2],p[0][3]));
      float m1 = fmaxf(fmaxf(p[1][0],p[1][1]), fmaxf(p[1][2],p[1][3]));
      float m2 = fmaxf(fmaxf(p[2][0],p[2][1]), fmaxf(p[2][2],p[2][3]));
      float m3 = fmaxf(fmaxf(p[3][0],p[3][1]), fmaxf(p[3][2],p[3][3]));
      tmax = fmaxf(fmaxf(m0,m1), fmaxf(m2,m3));
      tmax = fmaxf(tmax, __shfl_xor(tmax, 16));
      tmax = fmaxf(tmax, __shfl_xor(tmax, 32));
    }
    // defer-rescale (T13): only rescale when max grows by > 8 (log2 units)
    if(__any(tmax > mrow + 8.f)){
      float mn = fmaxf(mrow, tmax);
      float scal = exp2v(mrow - mn);
      mrow = mn;
      lrow *= scal;
      float so0 = __shfl(scal, lg*4 + 0);
      float so1 = __shfl(scal, lg*4 + 1);
      float so2 = __shfl(scal, lg*4 + 2);
      float so3 = __shfl(scal, lg*4 + 3);
      #pragma unroll
      for(int d=0; d<4; d++){
        oacc[d][0] *= so0; oacc[d][1] *= so1; oacc[d][2] *= so2; oacc[d][3] *= so3;
      }
    }
    // exp2 + sum + pack + P->LDS (per-wave, swizzled)
    {
      float rs = 0.f;
      #pragma unroll
      for(int f=0; f<4; f++){
        float e0 = exp2v(p[f][0] - mrow);
        float e1 = exp2v(p[f][1] - mrow);
        float e2 = exp2v(p[f][2] - mrow);
        float e3 = exp2v(p[f][3] - mrow);
        rs += (e0 + e1) + (e2 + e3);
        unsigned int a0 = cvtpk(e0, e1);
        unsigned int a1 = cvtpk(e2, e3);
        int blk = (f*2 + (lg >> 1)) ^ li7;
        uint2 w2; w2.x = a0; w2.y = a1;
        *(uint2*)&Psm[wid][li][blk*8 + (lg & 1)*4] = w2;
      }
      lrow += rs;
    }
    // O += P V
    __builtin_amdgcn_s_setprio(1);
    #pragma unroll
    for(int ks=0; ks<2; ks++){
      bf16x8 pa = *(const bf16x8*)&Psm[wid][li][((ks*4 + lg) ^ li7)*8];
      #pragma unroll
      for(int d=0; d<4; d++){
        int blk = (ks*4 + lg) ^ li7;
        bf16x8 vf = *(const bf16x8*)&Vsm[buf][(d*16 + li)*64 + blk*8];
        oacc[d] = mfma16(pa, vf, oacc[d]);
      }
    }
    __builtin_amdgcn_s_setprio(0);
    __syncthreads();
    mw = mwn;
    buf ^= 1;
  }
  // reduce lane-partial sums across the quad, normalize, store
  float rs = lrow;
  rs += __shfl_xor(rs, 16);
  rs += __shfl_xor(rs, 32);
  float inv = 1.0f / rs;                 // valid for q-row li
  float io0 = __shfl(inv, lg*4 + 0);
  float io1 = __shfl(inv, lg*4 + 1);
  float io2 = __shfl(inv, lg*4 + 2);
  float io3 = __shfl(inv, lg*4 + 3);
  #pragma unroll
  for(int d=0; d<4; d++){
    size_t rb = (size_t)(b*2048 + q0 + wid*16 + lg*4);
    O[(rb+0)*1024 + h*64 + 16*d + li] = f2bf(oacc[d][0] * io0);
    O[(rb+1)*1024 + h*64 + 16*d + li] = f2bf(oacc[d][1] * io1);
    O[(rb+2)*1024 + h*64 + 16*d + li] = f2bf(oacc[d][2] * io2);
    O[(rb+3)*1024 + h*64 + 16*d + li] = f2bf(oacc[d][3] * io3);
  }
}

// ---------- launch ----------
extern "C" void kernel_launch(void* const* d_in, const int* in_sizes, int n_in,
                              void* d_out, int out_size, void* d_ws, size_t ws_size,
                              hipStream_t stream)
{
  const float* q_in = (const float*)d_in[0];
  const float* k_in = (const float*)d_in[1];
  const float* v_in = (const float*)d_in[2];
  const unsigned char* mask = (const unsigned char*)d_in[3];
  const float* Wq = (const float*)d_in[4];
  const float* Wk = (const float*)d_in[5];
  const float* Wv = (const float*)d_in[6];
  const float* Wo = (const float*)d_in[7];

  char* ws = (char*)d_ws;
  const size_t MB = 1024*1024;
  int* flag          = (int*)ws;                              // 256 B
  unsigned short* XQ = (unsigned short*)(ws + 256);           // 8 MB
  unsigned short* XK = (unsigned short*)(ws + 256 + 8*MB);    // 8 MB
  unsigned short* XV = (unsigned short*)(ws + 256 + 16*MB);   // 8 MB
  unsigned short* WT = (unsigned short*)(ws + 256 + 24*MB);   // 8 MB (4 matrices)
  unsigned short* Qb = (unsigned short*)(ws + 256 + 32*MB);   // 8 MB
  unsigned short* Kb = (unsigned short*)(ws + 256 + 40*MB);   // 8 MB
  unsigned short* Vb = (unsigned short*)(ws + 256 + 48*MB);   // 8 MB
  unsigned short* Ob = XQ;                                    // attention output
  unsigned short* Vt = XK;                                    // transposed V (8 MB)
  unsigned int*   mpk= (unsigned int*)XV;                     // packed mask (2 MB)

  detect_kernel<<<1, 256, 0, stream>>>((const unsigned int*)mask, flag);
  cvt_kernel<<<2048, 256, 0, stream>>>(q_in, XQ);
  cvt_kernel<<<2048, 256, 0, stream>>>(k_in, XK);
  cvt_kernel<<<2048, 256, 0, stream>>>(v_in, XV);
  transW_kernel<<<dim3(256,4), 256, 0, stream>>>(Wq, Wk, Wv, Wo, WT);
  gemm_bt<0><<<dim3(32,8,3), 256, 0, stream>>>(XQ, XK, XV,
                                               WT, WT + 1048576, WT + 2097152,
                                               Qb, Kb, Vb, nullptr);
  transV_kernel<<<dim3(32,32), 256, 0, stream>>>(Vb, Vt);
  pack_mask_kernel<<<1024, 256, 0, stream>>>(mask, mpk, flag);
  attn_kernel<<<1024, 256, 0, stream>>>(Qb, Kb, Vt, Ob, mpk);
  gemm_bt<1><<<dim3(32,8,1), 256, 0, stream>>>(Ob, Ob, Ob,
                                               WT + 3*1048576, WT + 3*1048576, WT + 3*1048576,
                                               nullptr, nullptr, nullptr, (float*)d_out);
}